// Round 1
// baseline (1255.986 us; speedup 1.0000x reference)
//
#include <hip/hip_runtime.h>

// WiredRNN one step.
// inputs: 0:x(B,512) 1:states(B,N) 2:weight(E) 3:bias(N) 4:response(N)
//         5:edge_src(E int32) 6:edge_dst(E int32)
// out: y(B,256) then new_states(B,N), f32, concatenated flat.

#define BATCH 32
#define N_IN 512
#define N_OUT 256

// One thread per edge; loop over batch. agg in (B,N) layout (matches output).
__global__ void edge_kernel(const float* __restrict__ states,
                            const float* __restrict__ weight,
                            const int* __restrict__ edge_src,
                            const int* __restrict__ edge_dst,
                            float* __restrict__ agg,
                            int E, int N) {
    int e = blockIdx.x * blockDim.x + threadIdx.x;
    if (e >= E) return;
    int s = edge_src[e];
    int d = edge_dst[e];
    float w = weight[e];
    const float* sp = states + s;
    float* ap = agg + d;
    size_t stride = (size_t)N;
#pragma unroll
    for (int b = 0; b < BATCH; ++b) {
        atomicAdd(ap + (size_t)b * stride, w * sp[(size_t)b * stride]);
    }
}

// z = tanh(bias + response*agg); clamp first N_IN to x; write new_states and y.
__global__ void finish_kernel(const float* __restrict__ x,
                              const float* __restrict__ agg,
                              const float* __restrict__ bias,
                              const float* __restrict__ response,
                              float* __restrict__ y,   // (B, N_OUT)
                              float* __restrict__ ns,  // (B, N)
                              int N) {
    int n = blockIdx.x * blockDim.x + threadIdx.x;
    int b = blockIdx.y;
    if (n >= N) return;
    float v;
    if (n < N_IN) {
        v = x[b * N_IN + n];
    } else {
        v = tanhf(bias[n] + response[n] * agg[(size_t)b * N + n]);
    }
    ns[(size_t)b * N + n] = v;
    int n0 = N - N_OUT;
    if (n >= n0) {
        y[b * N_OUT + (n - n0)] = v;
    }
}

extern "C" void kernel_launch(void* const* d_in, const int* in_sizes, int n_in,
                              void* d_out, int out_size, void* d_ws, size_t ws_size,
                              hipStream_t stream) {
    const float* x        = (const float*)d_in[0];
    const float* states   = (const float*)d_in[1];
    const float* weight   = (const float*)d_in[2];
    const float* bias     = (const float*)d_in[3];
    const float* response = (const float*)d_in[4];
    const int*   edge_src = (const int*)d_in[5];
    const int*   edge_dst = (const int*)d_in[6];

    int N = in_sizes[3];          // 50000
    int E = in_sizes[5];          // 800000

    float* agg = (float*)d_ws;    // (B, N) f32 = 6.4 MB
    float* y   = (float*)d_out;                    // (B, N_OUT)
    float* ns  = (float*)d_out + BATCH * N_OUT;    // (B, N)

    // zero agg (required every call: accumulation target)
    hipMemsetAsync(agg, 0, (size_t)BATCH * N * sizeof(float), stream);

    int blk = 256;
    int egrid = (E + blk - 1) / blk;
    edge_kernel<<<egrid, blk, 0, stream>>>(states, weight, edge_src, edge_dst,
                                           agg, E, N);

    dim3 fgrid((N + blk - 1) / blk, BATCH);
    finish_kernel<<<fgrid, blk, 0, stream>>>(x, agg, bias, response, y, ns, N);
}

// Round 2
// 168.869 us; speedup vs baseline: 7.4376x; 7.4376x over previous
//
#include <hip/hip_runtime.h>

// WiredRNN one step, CSR-by-dst gather formulation.
// inputs: 0:x(B,512) 1:states(B,N) 2:weight(E) 3:bias(N) 4:response(N)
//         5:edge_src(E int32) 6:edge_dst(E int32)
// out: y(B,256) then new_states(B,N), f32, concatenated flat.

#define BATCH 32
#define N_IN 512
#define N_OUT 256

// ---------------- transpose states (B,N) -> statesT (N,32) ----------------
__global__ void transpose_in_kernel(const float* __restrict__ s,
                                    float* __restrict__ sT, int N) {
    __shared__ float tile[32][33];
    int n0 = blockIdx.x * 32;
    int tx = threadIdx.x;   // 0..31
    int ty = threadIdx.y;   // 0..7
    for (int i = ty; i < 32; i += 8) {           // i = b
        int n = n0 + tx;
        tile[i][tx] = (n < N) ? s[(size_t)i * N + n] : 0.f;
    }
    __syncthreads();
    for (int i = ty; i < 32; i += 8) {           // i = n_local
        int n = n0 + i;
        if (n < N) sT[(size_t)n * 32 + tx] = tile[tx][i];  // b = tx coalesced
    }
}

// ---------------- CSR build ----------------
__global__ void hist_kernel(const int* __restrict__ edge_dst,
                            int* __restrict__ counts, int E) {
    int e = blockIdx.x * blockDim.x + threadIdx.x;
    if (e >= E) return;
    int d = edge_dst[e];
    if (d >= N_IN) atomicAdd(&counts[d], 1);   // dst<N_IN results are clamped away
}

__global__ void scan1_kernel(const int* __restrict__ counts,
                             int* __restrict__ offsets,
                             int* __restrict__ blocksums, int N) {
    __shared__ int lds[256];
    int i = blockIdx.x * 256 + threadIdx.x;
    int v = (i < N) ? counts[i] : 0;
    lds[threadIdx.x] = v;
    __syncthreads();
    for (int off = 1; off < 256; off <<= 1) {
        int t = (threadIdx.x >= (unsigned)off) ? lds[threadIdx.x - off] : 0;
        __syncthreads();
        lds[threadIdx.x] += t;
        __syncthreads();
    }
    if (i < N) offsets[i] = lds[threadIdx.x] - v;       // exclusive (block-local)
    if (threadIdx.x == 255) blocksums[blockIdx.x] = lds[255];
}

__global__ void scan2_kernel(int* __restrict__ blocksums, int nblk) {
    __shared__ int lds[256];
    int v = (threadIdx.x < (unsigned)nblk) ? blocksums[threadIdx.x] : 0;
    lds[threadIdx.x] = v;
    __syncthreads();
    for (int off = 1; off < 256; off <<= 1) {
        int t = (threadIdx.x >= (unsigned)off) ? lds[threadIdx.x - off] : 0;
        __syncthreads();
        lds[threadIdx.x] += t;
        __syncthreads();
    }
    if (threadIdx.x < (unsigned)nblk) blocksums[threadIdx.x] = lds[threadIdx.x] - v; // exclusive
}

__global__ void scan3_kernel(int* __restrict__ offsets,
                             const int* __restrict__ blocksums, int N) {
    int i = blockIdx.x * 256 + threadIdx.x;
    if (i < N) offsets[i] += blocksums[blockIdx.x];
}

// fill: offsets acts as cursor; afterwards offsets[d] == end(d), start(d)=offsets[d-1]
__global__ void fill_kernel(const int* __restrict__ edge_src,
                            const int* __restrict__ edge_dst,
                            const float* __restrict__ weight,
                            int* __restrict__ offsets,
                            int2* __restrict__ edata, int E) {
    int e = blockIdx.x * blockDim.x + threadIdx.x;
    if (e >= E) return;
    int d = edge_dst[e];
    if (d < N_IN) return;
    int pos = atomicAdd(&offsets[d], 1);
    edata[pos] = make_int2(edge_src[e], __float_as_int(weight[e]));
}

// ---------------- aggregate + activation, one wave per node ----------------
__global__ void agg_kernel(const float* __restrict__ statesT,
                           const int2* __restrict__ edata,
                           const int* __restrict__ offsets,
                           const float* __restrict__ x,
                           const float* __restrict__ bias,
                           const float* __restrict__ response,
                           float* __restrict__ nsT, int N) {
    int node = blockIdx.x * (blockDim.x >> 6) + (threadIdx.x >> 6);
    if (node >= N) return;
    int lane = threadIdx.x & 63;
    int b = lane & 31;        // batch
    int p = lane >> 5;        // edge parity within wave
    if (node < N_IN) {
        if (p == 0) nsT[(size_t)node * 32 + b] = x[b * N_IN + node];
        return;
    }
    int end   = offsets[node];          // mutated by fill -> end of bucket
    int start = offsets[node - 1];      // end of previous bucket == our start
    float acc = 0.f;
    for (int e = start + p; e < end; e += 2) {
        int2 ed = edata[e];                                   // broadcast load
        acc += __int_as_float(ed.y) * statesT[(size_t)ed.x * 32 + b]; // 128B/edge
    }
    acc += __shfl_xor(acc, 32, 64);
    if (p == 0) {
        float z = tanhf(bias[node] + response[node] * acc);
        nsT[(size_t)node * 32 + b] = z;
    }
}

// ---------------- transpose nsT (N,32) -> ns (B,N), extract y ----------------
__global__ void transpose_out_kernel(const float* __restrict__ nsT,
                                     float* __restrict__ ns,
                                     float* __restrict__ y, int N) {
    __shared__ float tile[32][33];
    int n0 = blockIdx.x * 32;
    int tx = threadIdx.x;   // 0..31
    int ty = threadIdx.y;   // 0..7
    for (int i = ty; i < 32; i += 8) {           // i = n_local
        int n = n0 + i;
        tile[i][tx] = (n < N) ? nsT[(size_t)n * 32 + tx] : 0.f;  // b = tx
    }
    __syncthreads();
    for (int i = ty; i < 32; i += 8) {           // i = b
        int n = n0 + tx;
        if (n < N) {
            float v = tile[tx][i];
            ns[(size_t)i * N + n] = v;
            int k = n - (N - N_OUT);
            if (k >= 0) y[i * N_OUT + k] = v;
        }
    }
}

// ---------------- fallback (round-1) kernels ----------------
__global__ void edge_kernel_fb(const float* __restrict__ states,
                               const float* __restrict__ weight,
                               const int* __restrict__ edge_src,
                               const int* __restrict__ edge_dst,
                               float* __restrict__ agg, int E, int N) {
    int e = blockIdx.x * blockDim.x + threadIdx.x;
    if (e >= E) return;
    int s = edge_src[e];
    int d = edge_dst[e];
    float w = weight[e];
#pragma unroll
    for (int b = 0; b < BATCH; ++b)
        atomicAdd(agg + (size_t)b * N + d, w * states[(size_t)b * N + s]);
}

__global__ void finish_kernel_fb(const float* __restrict__ x,
                                 const float* __restrict__ agg,
                                 const float* __restrict__ bias,
                                 const float* __restrict__ response,
                                 float* __restrict__ y, float* __restrict__ ns,
                                 int N) {
    int n = blockIdx.x * blockDim.x + threadIdx.x;
    int b = blockIdx.y;
    if (n >= N) return;
    float v;
    if (n < N_IN) v = x[b * N_IN + n];
    else          v = tanhf(bias[n] + response[n] * agg[(size_t)b * N + n]);
    ns[(size_t)b * N + n] = v;
    int n0 = N - N_OUT;
    if (n >= n0) y[b * N_OUT + (n - n0)] = v;
}

extern "C" void kernel_launch(void* const* d_in, const int* in_sizes, int n_in,
                              void* d_out, int out_size, void* d_ws, size_t ws_size,
                              hipStream_t stream) {
    const float* x        = (const float*)d_in[0];
    const float* states   = (const float*)d_in[1];
    const float* weight   = (const float*)d_in[2];
    const float* bias     = (const float*)d_in[3];
    const float* response = (const float*)d_in[4];
    const int*   edge_src = (const int*)d_in[5];
    const int*   edge_dst = (const int*)d_in[6];

    int N = in_sizes[3];          // 50000
    int E = in_sizes[5];          // 800000

    float* y  = (float*)d_out;                   // (B, N_OUT)
    float* ns = (float*)d_out + BATCH * N_OUT;   // (B, N)

    const int blk = 256;
    int nblk_scan = (N + 255) / 256;             // 196

    // workspace layout (8B-aligned first)
    size_t edata_bytes   = (size_t)E * 8;
    size_t statesT_bytes = (size_t)N * 32 * 4;
    size_t nsT_bytes     = (size_t)N * 32 * 4;
    size_t counts_bytes  = (size_t)N * 4;
    size_t offs_bytes    = (size_t)(N + 1) * 4;
    size_t bsum_bytes    = 256 * 4;
    size_t needed = edata_bytes + statesT_bytes + nsT_bytes + counts_bytes +
                    offs_bytes + bsum_bytes + 64;

    if (ws_size < needed) {
        // fallback: round-1 atomic path (needs 6.4 MB)
        float* agg = (float*)d_ws;
        hipMemsetAsync(agg, 0, (size_t)BATCH * N * sizeof(float), stream);
        int egrid = (E + blk - 1) / blk;
        edge_kernel_fb<<<egrid, blk, 0, stream>>>(states, weight, edge_src,
                                                  edge_dst, agg, E, N);
        dim3 fgrid((N + blk - 1) / blk, BATCH);
        finish_kernel_fb<<<fgrid, blk, 0, stream>>>(x, agg, bias, response, y, ns, N);
        return;
    }

    char* p = (char*)d_ws;
    int2*  edata   = (int2*)p;            p += edata_bytes;
    float* statesT = (float*)p;           p += statesT_bytes;
    float* nsT     = (float*)p;           p += nsT_bytes;
    int*   counts  = (int*)p;             p += counts_bytes;
    int*   offsets = (int*)p;             p += offs_bytes;
    int*   bsums   = (int*)p;             p += bsum_bytes;

    hipMemsetAsync(counts, 0, counts_bytes, stream);

    int tgrid = (N + 31) / 32;
    transpose_in_kernel<<<tgrid, dim3(32, 8), 0, stream>>>(states, statesT, N);

    int egrid = (E + blk - 1) / blk;
    hist_kernel<<<egrid, blk, 0, stream>>>(edge_dst, counts, E);

    scan1_kernel<<<nblk_scan, 256, 0, stream>>>(counts, offsets, bsums, N);
    scan2_kernel<<<1, 256, 0, stream>>>(bsums, nblk_scan);
    scan3_kernel<<<nblk_scan, 256, 0, stream>>>(offsets, bsums, N);

    fill_kernel<<<egrid, blk, 0, stream>>>(edge_src, edge_dst, weight,
                                           offsets, edata, E);

    int waves_per_blk = blk / 64;  // 4
    int agrid = (N + waves_per_blk - 1) / waves_per_blk;
    agg_kernel<<<agrid, blk, 0, stream>>>(statesT, edata, offsets, x,
                                          bias, response, nsT, N);

    transpose_out_kernel<<<tgrid, dim3(32, 8), 0, stream>>>(nsT, ns, y, N);
}

// Round 3
// 134.716 us; speedup vs baseline: 9.3232x; 1.2535x over previous
//
#include <hip/hip_runtime.h>

// WiredRNN one step, CSR-by-dst gather formulation, atomic-free fill (rank trick).
// inputs: 0:x(B,512) 1:states(B,N) 2:weight(E) 3:bias(N) 4:response(N)
//         5:edge_src(E int32) 6:edge_dst(E int32)
// out: y(B,256) then new_states(B,N), f32, concatenated flat.

#define BATCH 32
#define N_IN 512
#define N_OUT 256

// ---- phase1: grid-fused {transpose states (B,N)->(N,32)} + {hist + rank} ----
__global__ void phase1_kernel(const float* __restrict__ s,
                              float* __restrict__ sT, int N, int tgrid,
                              const int* __restrict__ edge_dst,
                              int* __restrict__ counts,
                              int* __restrict__ rank, int E) {
    if ((int)blockIdx.x < tgrid) {
        __shared__ float tile[32][33];
        int tx = threadIdx.x & 31;
        int ty = threadIdx.x >> 5;        // 0..7
        int n0 = blockIdx.x * 32;
        for (int i = ty; i < 32; i += 8) {            // i = b
            int n = n0 + tx;
            tile[i][tx] = (n < N) ? s[(size_t)i * N + n] : 0.f;
        }
        __syncthreads();
        for (int i = ty; i < 32; i += 8) {            // i = n_local
            int n = n0 + i;
            if (n < N) sT[(size_t)n * 32 + tx] = tile[tx][i];  // b = tx
        }
    } else {
        int e = (blockIdx.x - tgrid) * blockDim.x + threadIdx.x;
        if (e >= E) return;
        int d = edge_dst[e];
        if (d >= N_IN) rank[e] = atomicAdd(&counts[d], 1);
        // dst < N_IN results are clamped away -> skip those edges entirely
    }
}

// ---------------- scan (exclusive) over counts -> offsets ----------------
__global__ void scan1_kernel(const int* __restrict__ counts,
                             int* __restrict__ offsets,
                             int* __restrict__ blocksums, int N) {
    __shared__ int lds[256];
    int i = blockIdx.x * 256 + threadIdx.x;
    int v = (i < N) ? counts[i] : 0;
    lds[threadIdx.x] = v;
    __syncthreads();
    for (int off = 1; off < 256; off <<= 1) {
        int t = (threadIdx.x >= (unsigned)off) ? lds[threadIdx.x - off] : 0;
        __syncthreads();
        lds[threadIdx.x] += t;
        __syncthreads();
    }
    if (i < N) offsets[i] = lds[threadIdx.x] - v;   // block-local exclusive
    if (threadIdx.x == 255) blocksums[blockIdx.x] = lds[255];
}

__global__ void scan2_kernel(int* __restrict__ blocksums, int nblk) {
    __shared__ int lds[256];
    int v = (threadIdx.x < (unsigned)nblk) ? blocksums[threadIdx.x] : 0;
    lds[threadIdx.x] = v;
    __syncthreads();
    for (int off = 1; off < 256; off <<= 1) {
        int t = (threadIdx.x >= (unsigned)off) ? lds[threadIdx.x - off] : 0;
        __syncthreads();
        lds[threadIdx.x] += t;
        __syncthreads();
    }
    if (threadIdx.x < (unsigned)nblk) blocksums[threadIdx.x] = lds[threadIdx.x] - v;
}

__global__ void scan3_kernel(int* __restrict__ offsets,
                             const int* __restrict__ blocksums, int N) {
    int i = blockIdx.x * 256 + threadIdx.x;
    if (i < N) offsets[i] += blocksums[blockIdx.x];
}

// ---- fill: atomic-free placement, pos = offsets[d] + rank[e] ----
__global__ void fill_kernel(const int* __restrict__ edge_src,
                            const int* __restrict__ edge_dst,
                            const float* __restrict__ weight,
                            const int* __restrict__ rank,
                            const int* __restrict__ offsets,
                            int2* __restrict__ edata, int E) {
    int e = blockIdx.x * blockDim.x + threadIdx.x;
    if (e >= E) return;
    int d = edge_dst[e];
    if (d < N_IN) return;
    int pos = offsets[d] + rank[e];
    edata[pos] = make_int2(edge_src[e], __float_as_int(weight[e]));
}

// ---- fallback fill: atomic cursor (mutates offsets to bucket ends) ----
__global__ void fill_atomic_kernel(const int* __restrict__ edge_src,
                                   const int* __restrict__ edge_dst,
                                   const float* __restrict__ weight,
                                   int* __restrict__ offsets,
                                   int2* __restrict__ edata, int E) {
    int e = blockIdx.x * blockDim.x + threadIdx.x;
    if (e >= E) return;
    int d = edge_dst[e];
    if (d < N_IN) return;
    int pos = atomicAdd(&offsets[d], 1);
    edata[pos] = make_int2(edge_src[e], __float_as_int(weight[e]));
}

// ---- aggregate + activation, one wave per node ----
// mutated==0: beg = offsets[node];               (rank path: offsets pristine)
// mutated==1: beg = offsets[node] - counts[node] (atomic path: offsets==end)
__global__ void agg_kernel(const float* __restrict__ statesT,
                           const int2* __restrict__ edata,
                           const int* __restrict__ offsets,
                           const int* __restrict__ counts,
                           const float* __restrict__ x,
                           const float* __restrict__ bias,
                           const float* __restrict__ response,
                           float* __restrict__ nsT, int N, int mutated) {
    int node = blockIdx.x * (blockDim.x >> 6) + (threadIdx.x >> 6);
    if (node >= N) return;
    int lane = threadIdx.x & 63;
    int b = lane & 31;        // batch
    int p = lane >> 5;        // edge parity within wave
    if (node < N_IN) {
        if (p == 0) nsT[(size_t)node * 32 + b] = x[b * N_IN + node];
        return;
    }
    int cnt = counts[node];
    int off = offsets[node];
    int beg = mutated ? off - cnt : off;
    int end = beg + cnt;
    float acc = 0.f;
    for (int e = beg + p; e < end; e += 2) {
        int2 ed = edata[e];                                   // broadcast load
        acc += __int_as_float(ed.y) * statesT[(size_t)ed.x * 32 + b]; // 128B/edge
    }
    acc += __shfl_xor(acc, 32, 64);
    if (p == 0) {
        float z = tanhf(bias[node] + response[node] * acc);
        nsT[(size_t)node * 32 + b] = z;
    }
}

// ---- transpose nsT (N,32) -> ns (B,N), extract y ----
__global__ void transpose_out_kernel(const float* __restrict__ nsT,
                                     float* __restrict__ ns,
                                     float* __restrict__ y, int N) {
    __shared__ float tile[32][33];
    int n0 = blockIdx.x * 32;
    int tx = threadIdx.x;   // 0..31
    int ty = threadIdx.y;   // 0..7
    for (int i = ty; i < 32; i += 8) {           // i = n_local
        int n = n0 + i;
        tile[i][tx] = (n < N) ? nsT[(size_t)n * 32 + tx] : 0.f;  // b = tx
    }
    __syncthreads();
    for (int i = ty; i < 32; i += 8) {           // i = b
        int n = n0 + tx;
        if (n < N) {
            float v = tile[tx][i];
            ns[(size_t)i * N + n] = v;
            int k = n - (N - N_OUT);
            if (k >= 0) y[i * N_OUT + k] = v;
        }
    }
}

// ---- last-resort fallback (round-1) kernels ----
__global__ void edge_kernel_fb(const float* __restrict__ states,
                               const float* __restrict__ weight,
                               const int* __restrict__ edge_src,
                               const int* __restrict__ edge_dst,
                               float* __restrict__ agg, int E, int N) {
    int e = blockIdx.x * blockDim.x + threadIdx.x;
    if (e >= E) return;
    int s = edge_src[e];
    int d = edge_dst[e];
    float w = weight[e];
#pragma unroll
    for (int b = 0; b < BATCH; ++b)
        atomicAdd(agg + (size_t)b * N + d, w * states[(size_t)b * N + s]);
}

__global__ void finish_kernel_fb(const float* __restrict__ x,
                                 const float* __restrict__ agg,
                                 const float* __restrict__ bias,
                                 const float* __restrict__ response,
                                 float* __restrict__ y, float* __restrict__ ns,
                                 int N) {
    int n = blockIdx.x * blockDim.x + threadIdx.x;
    int b = blockIdx.y;
    if (n >= N) return;
    float v;
    if (n < N_IN) v = x[b * N_IN + n];
    else          v = tanhf(bias[n] + response[n] * agg[(size_t)b * N + n]);
    ns[(size_t)b * N + n] = v;
    int n0 = N - N_OUT;
    if (n >= n0) y[b * N_OUT + (n - n0)] = v;
}

extern "C" void kernel_launch(void* const* d_in, const int* in_sizes, int n_in,
                              void* d_out, int out_size, void* d_ws, size_t ws_size,
                              hipStream_t stream) {
    const float* x        = (const float*)d_in[0];
    const float* states   = (const float*)d_in[1];
    const float* weight   = (const float*)d_in[2];
    const float* bias     = (const float*)d_in[3];
    const float* response = (const float*)d_in[4];
    const int*   edge_src = (const int*)d_in[5];
    const int*   edge_dst = (const int*)d_in[6];

    int N = in_sizes[3];          // 50000
    int E = in_sizes[5];          // 800000

    float* y  = (float*)d_out;                   // (B, N_OUT)
    float* ns = (float*)d_out + BATCH * N_OUT;   // (B, N)

    const int blk = 256;
    int nblk_scan = (N + 255) / 256;
    int tgrid = (N + 31) / 32;
    int egrid = (E + blk - 1) / blk;

    // workspace layout
    size_t edata_bytes   = (size_t)E * 8;
    size_t rank_bytes    = (size_t)E * 4;
    size_t statesT_bytes = (size_t)N * 32 * 4;
    size_t nsT_bytes     = (size_t)N * 32 * 4;
    size_t counts_bytes  = (size_t)N * 4;
    size_t offs_bytes    = (size_t)(N + 1) * 4;
    size_t bsum_bytes    = (size_t)((N + 255) / 256 + 1) * 4;
    size_t base_needed   = edata_bytes + statesT_bytes + nsT_bytes +
                           counts_bytes + offs_bytes + bsum_bytes + 64;
    size_t rank_needed   = base_needed + rank_bytes;

    if (ws_size < base_needed) {
        // last resort: round-1 atomic path (needs 6.4 MB)
        float* agg = (float*)d_ws;
        hipMemsetAsync(agg, 0, (size_t)BATCH * N * sizeof(float), stream);
        edge_kernel_fb<<<egrid, blk, 0, stream>>>(states, weight, edge_src,
                                                  edge_dst, agg, E, N);
        dim3 fgrid((N + blk - 1) / blk, BATCH);
        finish_kernel_fb<<<fgrid, blk, 0, stream>>>(x, agg, bias, response, y, ns, N);
        return;
    }

    bool use_rank = (ws_size >= rank_needed);

    char* p = (char*)d_ws;
    int2*  edata   = (int2*)p;            p += edata_bytes;
    float* statesT = (float*)p;           p += statesT_bytes;
    float* nsT     = (float*)p;           p += nsT_bytes;
    int*   counts  = (int*)p;             p += counts_bytes;
    int*   offsets = (int*)p;             p += offs_bytes;
    int*   bsums   = (int*)p;             p += bsum_bytes;
    int*   rank    = (int*)p;             // only if use_rank

    hipMemsetAsync(counts, 0, counts_bytes, stream);

    // phase1: transpose || hist(+rank). rank unused in non-rank path, but
    // phase1 still computes counts; pass counts as rank sink? No—guard below.
    if (use_rank) {
        phase1_kernel<<<tgrid + egrid, blk, 0, stream>>>(
            states, statesT, N, tgrid, edge_dst, counts, rank, E);
    } else {
        // rank buffer missing: write ranks into edata area temporarily is
        // unsafe (fill writes it later) -> use a dummy: counts-only hist via
        // rank=nullptr not allowed; reuse offsets as scratch is unsafe.
        // Simplest: atomic-cursor path. phase1 with rank -> edata (as int*),
        // overwritten later by fill_atomic anyway? edata[pos] writes could
        // race with rank[e] reads -> don't. Use separate hist inside phase1:
        phase1_kernel<<<tgrid + egrid, blk, 0, stream>>>(
            states, statesT, N, tgrid, edge_dst, counts, (int*)edata, E);
        // (int*)edata used as rank sink here is safe: values never read in
        // atomic path, and fill_atomic overwrites edata afterwards.
    }

    scan1_kernel<<<nblk_scan, 256, 0, stream>>>(counts, offsets, bsums, N);
    scan2_kernel<<<1, 256, 0, stream>>>(bsums, nblk_scan);
    scan3_kernel<<<nblk_scan, 256, 0, stream>>>(offsets, bsums, N);

    int mutated;
    if (use_rank) {
        fill_kernel<<<egrid, blk, 0, stream>>>(edge_src, edge_dst, weight,
                                               rank, offsets, edata, E);
        mutated = 0;
    } else {
        fill_atomic_kernel<<<egrid, blk, 0, stream>>>(edge_src, edge_dst,
                                                      weight, offsets, edata, E);
        mutated = 1;
    }

    int waves_per_blk = blk / 64;  // 4
    int agrid = (N + waves_per_blk - 1) / waves_per_blk;
    agg_kernel<<<agrid, blk, 0, stream>>>(statesT, edata, offsets, counts, x,
                                          bias, response, nsT, N, mutated);

    transpose_out_kernel<<<tgrid, dim3(32, 8), 0, stream>>>(nsT, ns, y, N);
}

// Round 4
// 103.578 us; speedup vs baseline: 12.1260x; 1.3006x over previous
//
#include <hip/hip_runtime.h>

// WiredRNN one step. CSR-by-dst gather, LDS-partitioned histogram (no global
// atomics anywhere in the fast path).
// inputs: 0:x(B,512) 1:states(B,N) 2:weight(E) 3:bias(N) 4:response(N)
//         5:edge_src(E int32) 6:edge_dst(E int32)
// out: y(B,256) then new_states(B,N), f32, concatenated flat.

#define BATCH 32
#define N_IN 512
#define N_OUT 256
#define RB 2048      // bins per range (8 KB LDS histogram)
#define CC 16        // edge chunks

// ---- pass1: grid-fused {transpose states (B,N)->(N,32)} +
//             {partitioned LDS hist + local rank} ----
// grid.x = tgrid + R*CC. Block k>=tgrid: r = k%R (bin range), c = k/R (chunk).
__global__ void pass1_kernel(const float* __restrict__ s,
                             float* __restrict__ sT, int N, int tgrid,
                             const int* __restrict__ edge_dst,
                             int* __restrict__ pcounts,
                             unsigned short* __restrict__ rank,
                             int E, int R, int chunk) {
    __shared__ int shbuf[RB];            // 8 KB; transpose aliases first 4.2 KB
    if ((int)blockIdx.x < tgrid) {
        float* tile = (float*)shbuf;     // [32][33]
        int tx = threadIdx.x & 31;
        int ty = threadIdx.x >> 5;       // 0..7
        int n0 = blockIdx.x * 32;
        for (int i = ty; i < 32; i += 8) {            // i = b
            int n = n0 + tx;
            tile[i * 33 + tx] = (n < N) ? s[(size_t)i * N + n] : 0.f;
        }
        __syncthreads();
        for (int i = ty; i < 32; i += 8) {            // i = n_local
            int n = n0 + i;
            if (n < N) sT[(size_t)n * 32 + tx] = tile[tx * 33 + i];  // b = tx
        }
        return;
    }
    int k = blockIdx.x - tgrid;
    int r = k % R;
    int c = k / R;
    int base = r * RB;
    for (int i = threadIdx.x; i < RB; i += 256) shbuf[i] = 0;
    __syncthreads();
    int e0 = c * chunk;
    int e1 = min(e0 + chunk, E);
    for (int e = e0 + (int)threadIdx.x * 4; e < e1; e += 256 * 4) {
        if (e + 3 < e1) {
            int4 d4 = *reinterpret_cast<const int4*>(edge_dst + e);
            int dd[4] = {d4.x, d4.y, d4.z, d4.w};
#pragma unroll
            for (int j = 0; j < 4; ++j) {
                int d = dd[j];
                unsigned v = (unsigned)(d - base);
                if (v < RB && d >= N_IN)
                    rank[e + j] = (unsigned short)atomicAdd(&shbuf[v], 1);
            }
        } else {
            for (int j = 0; j < 4 && e + j < e1; ++j) {
                int d = edge_dst[e + j];
                unsigned v = (unsigned)(d - base);
                if (v < RB && d >= N_IN)
                    rank[e + j] = (unsigned short)atomicAdd(&shbuf[v], 1);
            }
        }
    }
    __syncthreads();
    // every (bin, c) slot written exactly once across the grid -> no memset
    for (int i = threadIdx.x; i < RB; i += 256)
        pcounts[(size_t)(base + i) * CC + c] = shbuf[i];
}

// ---- 3-stage exclusive scan over M = NBINS*CC ints, in place ----
__global__ void scanA_kernel(int* __restrict__ data, int* __restrict__ bsums,
                             int M) {
    __shared__ int lds[256];
    size_t base = (size_t)blockIdx.x * 2048 + (size_t)threadIdx.x * 8;
    int v[8];
    if (base + 8 <= (size_t)M) {
        int4 a = *reinterpret_cast<const int4*>(data + base);
        int4 b = *reinterpret_cast<const int4*>(data + base + 4);
        v[0]=a.x; v[1]=a.y; v[2]=a.z; v[3]=a.w;
        v[4]=b.x; v[5]=b.y; v[6]=b.z; v[7]=b.w;
    } else {
        for (int j = 0; j < 8; ++j)
            v[j] = (base + j < (size_t)M) ? data[base + j] : 0;
    }
    int s = 0;
#pragma unroll
    for (int j = 0; j < 8; ++j) s += v[j];
    lds[threadIdx.x] = s;
    __syncthreads();
    for (int off = 1; off < 256; off <<= 1) {
        int t = (threadIdx.x >= (unsigned)off) ? lds[threadIdx.x - off] : 0;
        __syncthreads();
        lds[threadIdx.x] += t;
        __syncthreads();
    }
    int run = lds[threadIdx.x] - s;     // exclusive prefix for this thread
    if (base + 8 <= (size_t)M) {
        int o[8];
#pragma unroll
        for (int j = 0; j < 8; ++j) { o[j] = run; run += v[j]; }
        *reinterpret_cast<int4*>(data + base)     = make_int4(o[0],o[1],o[2],o[3]);
        *reinterpret_cast<int4*>(data + base + 4) = make_int4(o[4],o[5],o[6],o[7]);
    } else {
        for (int j = 0; j < 8; ++j) {
            if (base + j < (size_t)M) data[base + j] = run;
            run += v[j];
        }
    }
    if (threadIdx.x == 255) bsums[blockIdx.x] = lds[255];
}

__global__ void scanB_kernel(int* __restrict__ bsums, int n) {
    __shared__ int lds[512];
    int v = ((int)threadIdx.x < n) ? bsums[threadIdx.x] : 0;
    lds[threadIdx.x] = v;
    __syncthreads();
    for (int off = 1; off < 512; off <<= 1) {
        int t = (threadIdx.x >= (unsigned)off) ? lds[threadIdx.x - off] : 0;
        __syncthreads();
        lds[threadIdx.x] += t;
        __syncthreads();
    }
    if ((int)threadIdx.x < n) bsums[threadIdx.x] = lds[threadIdx.x] - v;
}

__global__ void scanC_kernel(int* __restrict__ data,
                             const int* __restrict__ bsums, int M) {
    int add = bsums[blockIdx.x];
    if (add == 0) return;
    size_t base = (size_t)blockIdx.x * 2048 + (size_t)threadIdx.x * 8;
    if (base + 8 <= (size_t)M) {
        int4 a = *reinterpret_cast<const int4*>(data + base);
        int4 b = *reinterpret_cast<const int4*>(data + base + 4);
        a.x+=add; a.y+=add; a.z+=add; a.w+=add;
        b.x+=add; b.y+=add; b.z+=add; b.w+=add;
        *reinterpret_cast<int4*>(data + base)     = a;
        *reinterpret_cast<int4*>(data + base + 4) = b;
    } else {
        for (int j = 0; j < 8; ++j)
            if (base + j < (size_t)M) data[base + j] += add;
    }
}

// ---- fill: fully atomic-free, pos = offsets[d*CC + chunk(e)] + rank[e] ----
__global__ void fill2_kernel(const int* __restrict__ edge_src,
                             const int* __restrict__ edge_dst,
                             const float* __restrict__ weight,
                             const unsigned short* __restrict__ rank,
                             const int* __restrict__ offsets,
                             int2* __restrict__ edata, int E, int chunk) {
    int e = blockIdx.x * blockDim.x + threadIdx.x;
    if (e >= E) return;
    int d = edge_dst[e];
    if (d < N_IN) return;
    int c = e / chunk;
    int pos = offsets[(size_t)d * CC + c] + (int)rank[e];
    edata[pos] = make_int2(edge_src[e], __float_as_int(weight[e]));
}

// ---- aggregate + activation, one wave per node, 2-deep gather unroll ----
__global__ void agg2_kernel(const float* __restrict__ statesT,
                            const int2* __restrict__ edata,
                            const int* __restrict__ offsets,
                            const float* __restrict__ x,
                            const float* __restrict__ bias,
                            const float* __restrict__ response,
                            float* __restrict__ nsT, int N) {
    int node = blockIdx.x * (blockDim.x >> 6) + (threadIdx.x >> 6);
    if (node >= N) return;
    int lane = threadIdx.x & 63;
    int b = lane & 31;        // batch
    int p = lane >> 5;        // edge parity within wave
    if (node < N_IN) {
        if (p == 0) nsT[(size_t)node * 32 + b] = x[b * N_IN + node];
        return;
    }
    int beg = offsets[(size_t)node * CC];
    int end = offsets[(size_t)(node + 1) * CC];
    float acc = 0.f, acc2 = 0.f;
    int e = beg + p;
    for (; e + 2 < end; e += 4) {
        int2 ea = edata[e];
        int2 eb = edata[e + 2];
        acc  += __int_as_float(ea.y) * statesT[(size_t)ea.x * 32 + b];
        acc2 += __int_as_float(eb.y) * statesT[(size_t)eb.x * 32 + b];
    }
    if (e < end) {
        int2 ea = edata[e];
        acc += __int_as_float(ea.y) * statesT[(size_t)ea.x * 32 + b];
    }
    acc += acc2;
    acc += __shfl_xor(acc, 32, 64);
    if (p == 0) {
        float z = tanhf(bias[node] + response[node] * acc);
        nsT[(size_t)node * 32 + b] = z;
    }
}

// ---- transpose nsT (N,32) -> ns (B,N), extract y ----
__global__ void transpose_out_kernel(const float* __restrict__ nsT,
                                     float* __restrict__ ns,
                                     float* __restrict__ y, int N) {
    __shared__ float tile[32][33];
    int n0 = blockIdx.x * 32;
    int tx = threadIdx.x;   // 0..31
    int ty = threadIdx.y;   // 0..7
    for (int i = ty; i < 32; i += 8) {           // i = n_local
        int n = n0 + i;
        tile[i][tx] = (n < N) ? nsT[(size_t)n * 32 + tx] : 0.f;  // b = tx
    }
    __syncthreads();
    for (int i = ty; i < 32; i += 8) {           // i = b
        int n = n0 + tx;
        if (n < N) {
            float v = tile[tx][i];
            ns[(size_t)i * N + n] = v;
            int k = n - (N - N_OUT);
            if (k >= 0) y[i * N_OUT + k] = v;
        }
    }
}

// ---- last-resort fallback (round-1) kernels ----
__global__ void edge_kernel_fb(const float* __restrict__ states,
                               const float* __restrict__ weight,
                               const int* __restrict__ edge_src,
                               const int* __restrict__ edge_dst,
                               float* __restrict__ agg, int E, int N) {
    int e = blockIdx.x * blockDim.x + threadIdx.x;
    if (e >= E) return;
    int s = edge_src[e];
    int d = edge_dst[e];
    float w = weight[e];
#pragma unroll
    for (int b = 0; b < BATCH; ++b)
        atomicAdd(agg + (size_t)b * N + d, w * states[(size_t)b * N + s]);
}

__global__ void finish_kernel_fb(const float* __restrict__ x,
                                 const float* __restrict__ agg,
                                 const float* __restrict__ bias,
                                 const float* __restrict__ response,
                                 float* __restrict__ y, float* __restrict__ ns,
                                 int N) {
    int n = blockIdx.x * blockDim.x + threadIdx.x;
    int b = blockIdx.y;
    if (n >= N) return;
    float v;
    if (n < N_IN) v = x[b * N_IN + n];
    else          v = tanhf(bias[n] + response[n] * agg[(size_t)b * N + n]);
    ns[(size_t)b * N + n] = v;
    int n0 = N - N_OUT;
    if (n >= n0) y[b * N_OUT + (n - n0)] = v;
}

extern "C" void kernel_launch(void* const* d_in, const int* in_sizes, int n_in,
                              void* d_out, int out_size, void* d_ws, size_t ws_size,
                              hipStream_t stream) {
    const float* x        = (const float*)d_in[0];
    const float* states   = (const float*)d_in[1];
    const float* weight   = (const float*)d_in[2];
    const float* bias     = (const float*)d_in[3];
    const float* response = (const float*)d_in[4];
    const int*   edge_src = (const int*)d_in[5];
    const int*   edge_dst = (const int*)d_in[6];

    int N = in_sizes[3];          // 50000
    int E = in_sizes[5];          // 800000

    float* y  = (float*)d_out;                   // (B, N_OUT)
    float* ns = (float*)d_out + BATCH * N_OUT;   // (B, N)

    const int blk = 256;
    int tgrid = (N + 31) / 32;                   // 1563
    int egrid = (E + blk - 1) / blk;             // 3125

    int R     = (N + RB - 1) / RB;               // 25
    int NBINS = R * RB;                          // 51200
    int M     = NBINS * CC;                      // 819200
    int chunk = (((E + CC - 1) / CC) + 3) & ~3;  // 50000
    int nblkA = (M + 2047) / 2048;               // 400

    // workspace layout (sizes 16B-rounded); rank aliases nsT (disjoint lifetimes)
    size_t edata_bytes   = ((size_t)E * 8  + 15) & ~(size_t)15;
    size_t statesT_bytes = ((size_t)N * 32 * 4 + 15) & ~(size_t)15;
    size_t nsT_bytes     = ((size_t)N * 32 * 4 + 15) & ~(size_t)15;
    size_t pcounts_bytes = ((size_t)M * 4 + 15) & ~(size_t)15;
    size_t bsum_bytes    = ((size_t)nblkA * 4 + 15) & ~(size_t)15;
    size_t needed = edata_bytes + statesT_bytes + nsT_bytes + pcounts_bytes +
                    bsum_bytes + 64;
    bool rank_fits = ((size_t)E * 2 <= nsT_bytes);

    if (ws_size < needed || nblkA > 512 || !rank_fits) {
        // fallback: atomic-scatter path (needs 6.4 MB)
        float* agg = (float*)d_ws;
        hipMemsetAsync(agg, 0, (size_t)BATCH * N * sizeof(float), stream);
        edge_kernel_fb<<<egrid, blk, 0, stream>>>(states, weight, edge_src,
                                                  edge_dst, agg, E, N);
        dim3 fgrid((N + blk - 1) / blk, BATCH);
        finish_kernel_fb<<<fgrid, blk, 0, stream>>>(x, agg, bias, response,
                                                    y, ns, N);
        return;
    }

    char* p = (char*)d_ws;
    int2*  edata   = (int2*)p;            p += edata_bytes;
    float* statesT = (float*)p;           p += statesT_bytes;
    float* nsT     = (float*)p;           p += nsT_bytes;
    int*   pcounts = (int*)p;             p += pcounts_bytes;   // -> offsets (in-place scan)
    int*   bsums   = (int*)p;             p += bsum_bytes;
    unsigned short* rank = (unsigned short*)nsT;  // alias: live pass1 -> fill2

    // 1. transpose || partitioned hist+rank (no global atomics, no memset)
    pass1_kernel<<<tgrid + R * CC, blk, 0, stream>>>(
        states, statesT, N, tgrid, edge_dst, pcounts, rank, E, R, chunk);

    // 2. exclusive scan of pcounts (bin-major, chunk-minor), in place
    scanA_kernel<<<nblkA, 256, 0, stream>>>(pcounts, bsums, M);
    scanB_kernel<<<1, 512, 0, stream>>>(bsums, nblkA);
    scanC_kernel<<<nblkA, 256, 0, stream>>>(pcounts, bsums, M);

    // 3. atomic-free placement
    fill2_kernel<<<egrid, blk, 0, stream>>>(edge_src, edge_dst, weight,
                                            rank, pcounts, edata, E, chunk);

    // 4. gather-aggregate + tanh (clobbers rank via nsT — fill2 already done)
    int waves_per_blk = blk / 64;  // 4
    int agrid = (N + waves_per_blk - 1) / waves_per_blk;
    agg2_kernel<<<agrid, blk, 0, stream>>>(statesT, edata, pcounts, x,
                                           bias, response, nsT, N);

    // 5. transpose out + y slice
    transpose_out_kernel<<<tgrid, dim3(32, 8), 0, stream>>>(nsT, ns, y, N);
}